// Round 4
// baseline (4765.276 us; speedup 1.0000x reference)
//
#include <hip/hip_runtime.h>
#include <hip/hip_fp16.h>

#define NN 100000
#define NE 1600000
#define KORD 10
#define HID 64

// binned CSR build: 391 buckets of 256 destination nodes each
#define NBUK ((NN + 255) / 256)        // 391
#define BCAP 8192                      // per-bucket staging capacity (mean 4096, sd 64)
#define EPB  (NE / 256)                // 6250 edges per pass-A block (256 blocks exactly)
// padded CSR capacity: every node segment rounded up to 8 entries
#define CSR_CAP (NE + 8 * NN)          // 2.4M entries

// channel slicing: 4 slices x 16 channels, slice-major feature layout
// [slice][node][ch16] -> per-slice gather table = (NN+1)*32B = 3.2 MB (fits 4 MB XCD L2)
#define NSL 4
#define SROW (NN + 1)                  // rows per slice incl. sentinel
#define NBPS ((NN + 127) / 128)        // 782 chunks per slice (128 nodes/chunk)
#define NPROP 20                       // k_prop launches per run (2 layers x 10)

typedef _Float16 half8v __attribute__((ext_vector_type(8)));
typedef _Float16 half4v __attribute__((ext_vector_type(4)));
typedef float float4v __attribute__((ext_vector_type(4)));
typedef unsigned uint4v __attribute__((ext_vector_type(4)));
typedef int int4v __attribute__((ext_vector_type(4)));

__device__ __forceinline__ float2 up2(unsigned u) {
    __half2 hh = *(__half2*)&u;
    return __half22float2(hh);
}
__device__ __forceinline__ unsigned pk2(float a, float b) {
    __half2 hh = __floats2half2_rn(a, b);
    return *(unsigned*)&hh;
}

// ---------------- binned CSR build ----------------
__global__ __launch_bounds__(512) void k_zero(int* __restrict__ gcnt,
                                              int* __restrict__ dhist,
                                              int* __restrict__ palloc,
                                              int* __restrict__ qcnt) {
    int t = threadIdx.x;
    if (t < NBUK) gcnt[t] = 0;
    if (t < 64) dhist[t] = 0;
    if (t == 511) *palloc = 0;
    if (t < NPROP * NSL) qcnt[t] = 0;
}

// pass A: partition edges into per-destination-range buckets.
// record = (c & 255) << 24 | r   (r < 2^24 since NN = 100000)
__global__ __launch_bounds__(1024) void k_binA(const int* __restrict__ ei,
                                               int* __restrict__ gcnt,
                                               unsigned* __restrict__ staged) {
    __shared__ int lh[NBUK];
    __shared__ int lcur[NBUK];
    int t = threadIdx.x;
    int ebeg = blockIdx.x * EPB;
    int eend = min(ebeg + EPB, NE);
    for (int i = t; i < NBUK; i += 1024) lh[i] = 0;
    __syncthreads();
    for (int e = ebeg + t; e < eend; e += 1024)
        atomicAdd(&lh[ei[NE + e] >> 8], 1);
    __syncthreads();
    for (int i = t; i < NBUK; i += 1024)
        lcur[i] = lh[i] ? atomicAdd(&gcnt[i], lh[i]) : 0;
    __syncthreads();
    for (int e = ebeg + t; e < eend; e += 1024) {
        int r = ei[e], c = ei[NE + e];
        int bkt = c >> 8;
        int slot = atomicAdd(&lcur[bkt], 1);
        if (slot < BCAP)
            staged[(size_t)bkt * BCAP + slot] = ((unsigned)(c & 255) << 24) | (unsigned)r;
    }
}

// pass B: one block per bucket. LDS histogram + padded scan over the 256-node
// range, bucket base via global atomic allocator, then scatter into the
// bucket's contiguous csr window (L2-local writes). Node segments are
// 8-aligned and tail-padded with sentinel NN (zero row) so the gather loop
// is fully branchless. Emits cnt / dinv / seg{start,iters} for the range.
__global__ __launch_bounds__(512) void k_binB(const unsigned* __restrict__ staged,
                                              const int* __restrict__ gcnt,
                                              int* __restrict__ palloc,
                                              int* __restrict__ cnt,
                                              float* __restrict__ dinv,
                                              int* __restrict__ csr,
                                              int2* __restrict__ seg) {
    __shared__ unsigned lrec[BCAP];
    __shared__ int lcnt[256], lcur[256], ltmp[256];
    __shared__ int lbase;
    int b = blockIdx.x, t = threadIdx.x;
    int count = min(gcnt[b], BCAP);
    if (t < 256) lcnt[t] = 0;
    __syncthreads();
    for (int i = t; i < count; i += 512) {
        unsigned rec = staged[(size_t)b * BCAP + i];
        lrec[i] = rec;
        atomicAdd(&lcnt[rec >> 24], 1);
    }
    __syncthreads();
    int v = 0, plen = 0;
    if (t < 256) { v = lcnt[t]; plen = (v + 7) & ~7; ltmp[t] = plen; }
    __syncthreads();
    int x = plen;
    for (int off = 1; off < 256; off <<= 1) {
        int y = (t < 256 && t >= off) ? ltmp[t - off] : 0;
        __syncthreads();
        if (t < 256) { x += y; ltmp[t] = x; }
        __syncthreads();
    }
    if (t == 255) lbase = atomicAdd(palloc, x);   // x = padded bucket total
    __syncthreads();
    int start = 0;
    if (t < 256) {
        start = lbase + x - plen;
        lcur[t] = start;
        int node = b * 256 + t;
        if (node < NN) {
            cnt[node] = v;
            dinv[node] = rsqrtf((float)(v + 1));   // +1 self-loop
            seg[node] = make_int2(start, plen >> 3);
            for (int i = v; i < plen; ++i) csr[start + i] = NN;   // sentinel pad
        }
    }
    __syncthreads();
    for (int i = t; i < count; i += 512) {
        unsigned rec = lrec[i];
        int pos = atomicAdd(&lcur[rec >> 24], 1);
        csr[pos] = (int)(rec & 0xFFFFFFu);
    }
}

// ---------------- degree-sorted node permutation ----------------
__global__ __launch_bounds__(256) void k_dhist(const int* __restrict__ cnt,
                                               int* __restrict__ dhist) {
    __shared__ int lh[64];
    int t = threadIdx.x;
    if (t < 64) lh[t] = 0;
    __syncthreads();
    int i = blockIdx.x * 256 + t;
    if (i < NN) atomicAdd(&lh[min(cnt[i], 63)], 1);
    __syncthreads();
    if (t < 64 && lh[t]) atomicAdd(&dhist[t], lh[t]);
}

__global__ void k_dscan(int* __restrict__ dhist) {   // 64 threads, exclusive scan
    __shared__ int tmp[64];
    int t = threadIdx.x;
    int v = dhist[t];
    tmp[t] = v;
    __syncthreads();
    int x = v;
    for (int off = 1; off < 64; off <<= 1) {
        int y = (t >= off) ? tmp[t - off] : 0;
        __syncthreads();
        x += y;
        tmp[t] = x;
        __syncthreads();
    }
    dhist[t] = x - v;
}

__global__ __launch_bounds__(256) void k_dperm(const int* __restrict__ cnt,
                                               int* __restrict__ dhist,
                                               int* __restrict__ perm) {
    __shared__ int lh[64], lb[64];
    int t = threadIdx.x;
    if (t < 64) lh[t] = 0;
    __syncthreads();
    int i = blockIdx.x * 256 + t;
    int b = 0, my = 0;
    if (i < NN) { b = min(cnt[i], 63); my = atomicAdd(&lh[b], 1); }
    __syncthreads();
    if (t < 64) lb[t] = lh[t] ? atomicAdd(&dhist[t], lh[t]) : 0;
    __syncthreads();
    if (i < NN) perm[lb[b] + my] = i;
}

// zero sentinel row NN of all 4 slices of the 4 rotation buffers
__global__ __launch_bounds__(256) void k_zrow(__half* __restrict__ a, __half* __restrict__ b,
                                              __half* __restrict__ c, __half* __restrict__ d) {
    int t = threadIdx.x;
    __half* bufs[4] = {a, b, c, d};
    int bi = t >> 6, s = (t >> 4) & 3, ch = t & 15;
    bufs[bi][((size_t)s * SROW + NN) * 16 + ch] = __float2half(0.f);
}

// ---------- W1 transpose + fp16 cast ----------
__global__ __launch_bounds__(256) void k_prepw1(const float* __restrict__ W1,
                                                _Float16* __restrict__ W1T) {
    int f = blockIdx.x * 256 + threadIdx.x;
    int n = f >> 8, k = f & 255;
    W1T[f] = (_Float16)W1[k * 64 + n];
}

// ---------- GEMM1 via MFMA: h~ = dinv * relu(x @ W1 + b1), slice-major out ----------
#define G1K 128
#define G1S 136
__global__ __launch_bounds__(256) void k_gemm1(const float* __restrict__ x,
                                               const _Float16* __restrict__ W1T,
                                               const float* __restrict__ b1,
                                               const float* __restrict__ dinv,
                                               __half* __restrict__ h) {
    __shared__ _Float16 A_lds[64 * G1S];
    __shared__ _Float16 B_lds[64 * G1S];
    int t = threadIdx.x;
    int wave = t >> 6, lane = t & 63;
    int quad = lane >> 4, m16 = lane & 15;
    int row0 = blockIdx.x * 64;

    float4v acc[4];
#pragma unroll
    for (int n4 = 0; n4 < 4; ++n4) acc[n4] = (float4v){0.f, 0.f, 0.f, 0.f};

    for (int c = 0; c < 2; ++c) {
        int k0 = c * G1K;
#pragma unroll
        for (int i = 0; i < 8; ++i) {
            int f = i * 256 + t;
            int r = f >> 5, c4 = f & 31;
            int grow = row0 + r;
            float4 v = (grow < NN) ? *(const float4*)&x[(size_t)grow * 256 + k0 + c4 * 4]
                                   : make_float4(0.f, 0.f, 0.f, 0.f);
            half4v hv = {(_Float16)v.x, (_Float16)v.y, (_Float16)v.z, (_Float16)v.w};
            *(half4v*)&A_lds[r * G1S + c4 * 4] = hv;
        }
#pragma unroll
        for (int i = 0; i < 4; ++i) {
            int f = i * 256 + t;
            int n = f >> 4, k8 = f & 15;
            *(half8v*)&B_lds[n * G1S + k8 * 8] =
                *(const half8v*)&W1T[n * 256 + k0 + k8 * 8];
        }
        __syncthreads();

#pragma unroll
        for (int s = 0; s < 4; ++s) {
            half8v af = *(const half8v*)&A_lds[(wave * 16 + m16) * G1S + s * 32 + quad * 8];
#pragma unroll
            for (int n4 = 0; n4 < 4; ++n4) {
                half8v bf = *(const half8v*)&B_lds[(n4 * 16 + m16) * G1S + s * 32 + quad * 8];
                acc[n4] = __builtin_amdgcn_mfma_f32_16x16x32_f16(af, bf, acc[n4], 0, 0, 0);
            }
        }
        __syncthreads();
    }

    float bv[4];
#pragma unroll
    for (int n4 = 0; n4 < 4; ++n4) bv[n4] = b1[n4 * 16 + m16];
#pragma unroll
    for (int r = 0; r < 4; ++r) {
        int grow = row0 + wave * 16 + quad * 4 + r;
        if (grow >= NN) continue;
        float dv = dinv[grow];
#pragma unroll
        for (int n4 = 0; n4 < 4; ++n4) {
            // channel = n4*16 + m16 -> slice n4, in-slice channel m16
            float v = dv * fmaxf(acc[n4][r] + bv[n4], 0.f);
            h[((size_t)n4 * SROW + grow) * 16 + m16] = __float2half(v);
        }
    }
}

// ---------- fused propagation + Jacobi combine (XCD-pinned channel slices) ----------
// Each block reads its REAL chiplet id (HW_REG_XCC_ID) and works on slice
// xcc>>1 so its 3.2 MB slice stays resident in that XCD's 4 MB L2. Work is
// distributed via per-slice atomic chunk queues; after a block's own queue
// drains it steals from other slices, so completion never depends on the
// block->XCD mapping. 2 lanes/node, 32 nodes/wave, branchless 8-wide gather
// (sentinel row NN absorbs padding). Streaming traffic is nontemporal so it
// cannot evict the resident slice.
#define ACC8(u) { float2 f0 = up2((u).x), f1 = up2((u).y), f2 = up2((u).z), f3 = up2((u).w); \
    p[0] += f0.x; p[1] += f0.y; p[2] += f1.x; p[3] += f1.y; \
    p[4] += f2.x; p[5] += f2.y; p[6] += f3.x; p[7] += f3.y; }

__global__ __launch_bounds__(256) void k_prop(const int2* __restrict__ seg,
                                              const int* __restrict__ csr,
                                              const int* __restrict__ perm,
                                              const __half* __restrict__ src,
                                              const __half* __restrict__ t0,
                                              const float* __restrict__ dinv,
                                              __half* __restrict__ dst,
                                              __half* __restrict__ acc,
                                              __half* __restrict__ hout,
                                              float An, float Bn, float Cn,
                                              const float* __restrict__ coeffs,
                                              int cbase, int kidx, int init,
                                              int finalize, int unscale,
                                              int* __restrict__ qcnt) {
    __shared__ int chunk_s;
    int t = threadIdx.x;
    int xcc;
    asm volatile("s_getreg_b32 %0, hwreg(HW_REG_XCC_ID)" : "=s"(xcc));
    int myslice = (xcc >> 1) & 3;

    for (int ss = 0; ss < NSL; ++ss) {
        int sl = (myslice + ss) & 3;
        int* q = qcnt + sl;
        const __half* sb = src + (size_t)sl * SROW * 16;
        while (true) {
            __syncthreads();
            if (t == 0) chunk_s = atomicAdd(q, 1);
            __syncthreads();
            int blk = chunk_s;
            if (blk >= NBPS) break;

            int slot = blk * 128 + (t >> 6) * 32 + ((t & 63) >> 1);
            int ch8 = (t & 1) * 8;
            bool valid = slot < NN;
            int node = valid ? perm[slot] : 0;
            int2 sg = valid ? seg[node] : make_int2(0, 0);
            const int4v* cp = (const int4v*)(csr + sg.x);
            int iters = sg.y;

            float p[8];
#pragma unroll
            for (int i = 0; i < 8; ++i) p[i] = 0.f;

            for (int it = 0; it < iters; ++it) {
                int4v ia = __builtin_nontemporal_load(&cp[it * 2]);
                int4v ib = __builtin_nontemporal_load(&cp[it * 2 + 1]);
                uint4v u0 = *(const uint4v*)&sb[ia.x * 16 + ch8];
                uint4v u1 = *(const uint4v*)&sb[ia.y * 16 + ch8];
                uint4v u2 = *(const uint4v*)&sb[ia.z * 16 + ch8];
                uint4v u3 = *(const uint4v*)&sb[ia.w * 16 + ch8];
                uint4v u4 = *(const uint4v*)&sb[ib.x * 16 + ch8];
                uint4v u5 = *(const uint4v*)&sb[ib.y * 16 + ch8];
                uint4v u6 = *(const uint4v*)&sb[ib.z * 16 + ch8];
                uint4v u7 = *(const uint4v*)&sb[ib.w * 16 + ch8];
                ACC8(u0); ACC8(u1); ACC8(u2); ACC8(u3);
                ACC8(u4); ACC8(u5); ACC8(u6); ACC8(u7);
            }

            if (valid) {
                size_t idx = ((size_t)sl * SROW + node) * 16 + ch8;
                float dv = dinv[node];
                float dv2 = dv * dv;

                uint4v sr = *(const uint4v*)&src[idx];          // resident slice row
                float2 s01 = up2(sr.x), s23 = up2(sr.y), s45 = up2(sr.z), s67 = up2(sr.w);
                float sv[8] = {s01.x, s01.y, s23.x, s23.y, s45.x, s45.y, s67.x, s67.y};

                uint4v trr = __builtin_nontemporal_load((const uint4v*)&t0[idx]);
                float2 t01 = up2(trr.x), t23 = up2(trr.y), t45 = up2(trr.z), t67 = up2(trr.w);
                float tv[8] = {t01.x, t01.y, t23.x, t23.y, t45.x, t45.y, t67.x, t67.y};

                float v[8];
#pragma unroll
                for (int i = 0; i < 8; ++i)
                    v[i] = An * dv2 * (p[i] + sv[i]) + Bn * sv[i] - Cn * tv[i];

                if (!finalize) {
                    uint4v o;
                    o.x = pk2(v[0], v[1]); o.y = pk2(v[2], v[3]);
                    o.z = pk2(v[4], v[5]); o.w = pk2(v[6], v[7]);
                    __builtin_nontemporal_store(o, (uint4v*)&dst[idx]);
                }

                float ck = coeffs[cbase + kidx];
                float av[8];
                if (init) {
                    float c0 = coeffs[cbase];
#pragma unroll
                    for (int i = 0; i < 8; ++i) av[i] = c0 * sv[i];
                } else {
                    uint4v ar = __builtin_nontemporal_load((const uint4v*)&acc[idx]);
                    float2 a01 = up2(ar.x), a23 = up2(ar.y), a45 = up2(ar.z), a67 = up2(ar.w);
                    av[0] = a01.x; av[1] = a01.y; av[2] = a23.x; av[3] = a23.y;
                    av[4] = a45.x; av[5] = a45.y; av[6] = a67.x; av[7] = a67.y;
                }
#pragma unroll
                for (int i = 0; i < 8; ++i) av[i] += ck * v[i];

                uint4v o;
                if (finalize) {
                    float s = unscale ? (1.0f / dv) : 1.0f;
                    o.x = pk2(s * fmaxf(av[0], 0.f), s * fmaxf(av[1], 0.f));
                    o.y = pk2(s * fmaxf(av[2], 0.f), s * fmaxf(av[3], 0.f));
                    o.z = pk2(s * fmaxf(av[4], 0.f), s * fmaxf(av[5], 0.f));
                    o.w = pk2(s * fmaxf(av[6], 0.f), s * fmaxf(av[7], 0.f));
                    __builtin_nontemporal_store(o, (uint4v*)&hout[idx]);
                } else {
                    o.x = pk2(av[0], av[1]); o.y = pk2(av[2], av[3]);
                    o.z = pk2(av[4], av[5]); o.w = pk2(av[6], av[7]);
                    __builtin_nontemporal_store(o, (uint4v*)&acc[idx]);
                }
            }
        }
    }
}

// ---------- GEMM2: out = h16 @ W2 + b2 (slice-major h) ----------
__global__ __launch_bounds__(256) void k_gemm2(const __half* __restrict__ h,
                                               const float* __restrict__ W2,
                                               const float* __restrict__ b2,
                                               float* __restrict__ out) {
    __shared__ float W2s[64 * 32];
    __shared__ float b2s[32];
    int t = threadIdx.x;
    for (int i = t * 4; i < 64 * 32; i += 256 * 4)
        *(float4*)&W2s[i] = *(const float4*)&W2[i];
    if (t < 32) b2s[t] = b2[t];
    __syncthreads();

    int gid = blockIdx.x * 256 + t;
    int row = gid >> 3;
    int c4 = (t & 7) * 4;
    if (row >= NN) return;
    float4 acc = *(const float4*)&b2s[c4];
#pragma unroll
    for (int s = 0; s < 4; ++s) {
        const __half* hr = h + ((size_t)s * SROW + row) * 16;
#pragma unroll
        for (int p8 = 0; p8 < 2; ++p8) {
            uint4 raw = *(const uint4*)&hr[p8 * 8];
            float2 a01 = up2(raw.x), a23 = up2(raw.y), a45 = up2(raw.z), a67 = up2(raw.w);
            float a[8] = {a01.x, a01.y, a23.x, a23.y, a45.x, a45.y, a67.x, a67.y};
#pragma unroll
            for (int j = 0; j < 8; ++j) {
                float4 w = *(const float4*)&W2s[(s * 16 + p8 * 8 + j) * 32 + c4];
                acc.x += a[j] * w.x;
                acc.y += a[j] * w.y;
                acc.z += a[j] * w.z;
                acc.w += a[j] * w.w;
            }
        }
    }
    *(float4*)&out[(size_t)row * 32 + c4] = acc;
}

extern "C" void kernel_launch(void* const* d_in, const int* in_sizes, int n_in,
                              void* d_out, int out_size, void* d_ws, size_t ws_size,
                              hipStream_t stream) {
    const float* x      = (const float*)d_in[0];
    const int*   ei     = (const int*)d_in[1];
    const float* W1     = (const float*)d_in[2];
    const float* b1     = (const float*)d_in[3];
    const float* coeffs = (const float*)d_in[4];
    const float* W2     = (const float*)d_in[5];
    const float* b2     = (const float*)d_in[6];
    float* out = (float*)d_out;

    char* ws = (char*)d_ws;
    size_t off = 0;
    auto alloc = [&](size_t bytes) { void* p = ws + off; off += (bytes + 255) & ~(size_t)255; return p; };
    int*      cnt    = (int*)alloc(NN * 4);
    float*    dinv   = (float*)alloc(NN * 4);
    int*      csr    = (int*)alloc((size_t)CSR_CAP * 4);
    int2*     seg    = (int2*)alloc((size_t)NN * 8);
    int*      dhist  = (int*)alloc(64 * 4);
    int*      perm   = (int*)alloc(NN * 4);
    int*      gcnt   = (int*)alloc(NBUK * 4);
    int*      palloc = (int*)alloc(4);
    int*      qcnt   = (int*)alloc(NPROP * NSL * 4);
    unsigned* staged = (unsigned*)alloc((size_t)NBUK * BCAP * 4);
    _Float16* W1T    = (_Float16*)alloc(256 * 64 * 2);
    __half*   h16    = (__half*)alloc((size_t)NSL * SROW * 16 * 2);
    __half*   bufA   = (__half*)alloc((size_t)NSL * SROW * 16 * 2);
    __half*   bufB   = (__half*)alloc((size_t)NSL * SROW * 16 * 2);
    __half*   bufC   = (__half*)alloc((size_t)NSL * SROW * 16 * 2);
    __half*   accb   = (__half*)alloc((size_t)NSL * SROW * 16 * 2);

    const int BN = (NN + 255) / 256;
    const int BPP = NBPS * NSL;             // 3128 blocks (one per chunk)

    // --- binned CSR build (write-local scatter, 8-aligned padded segments) ---
    k_zero<<<1, 512, 0, stream>>>(gcnt, dhist, palloc, qcnt);
    k_binA<<<256, 1024, 0, stream>>>(ei, gcnt, staged);
    k_binB<<<NBUK, 512, 0, stream>>>(staged, gcnt, palloc, cnt, dinv, csr, seg);

    // --- degree-sorted node permutation ---
    k_dhist<<<BN, 256, 0, stream>>>(cnt, dhist);
    k_dscan<<<1, 64, 0, stream>>>(dhist);
    k_dperm<<<BN, 256, 0, stream>>>(cnt, dhist, perm);
    k_zrow<<<1, 256, 0, stream>>>(h16, bufA, bufB, bufC);

    // --- h~ = dinv * relu(x @ W1 + b1) via MFMA ---
    k_prepw1<<<64, 256, 0, stream>>>(W1, W1T);
    k_gemm1<<<(NN + 63) / 64, 256, 0, stream>>>(x, W1T, b1, dinv, h16);

    __half* rot[4] = {h16, bufA, bufB, bufC};
    int pidx = 0;

    for (int l = 0; l < 2; ++l) {
        int cbase = l * (KORD + 1);
        k_prop<<<BPP, 256, 0, stream>>>(seg, csr, perm, rot[0], rot[0], dinv,
                                        rot[1], accb, h16, 1.0f, 0.0f, 0.0f,
                                        coeffs, cbase, 1, 1, 0, 0,
                                        qcnt + (pidx++) * NSL);
        for (int k = 2; k <= KORD; ++k) {
            __half* dst = rot[k & 3];
            const __half* s1 = rot[(k - 1) & 3];
            const __half* s0 = rot[(k - 2) & 3];
            double n = k - 1, a = 0.5, b = 0.5;
            double An = (2*n + a + b + 1) * (2*n + a + b + 2) / (2 * (n + 1) * (n + a + b + 1));
            double Bn = (a*a - b*b) * (2*n + a + b + 1) / (2 * (n + 1) * (n + a + b + 1) * (2*n + a + b));
            double Cn = (n + a) * (n + b) * (2*n + a + b + 2) / ((n + 1) * (n + a + b + 1) * (2*n + a + b));
            k_prop<<<BPP, 256, 0, stream>>>(seg, csr, perm, s1, s0, dinv,
                                            dst, accb, h16, (float)An, (float)Bn, (float)Cn,
                                            coeffs, cbase, k, 0,
                                            (k == KORD) ? 1 : 0, l,
                                            qcnt + (pidx++) * NSL);
        }
    }

    // out = h @ W2 + b2
    k_gemm2<<<(NN * 8 + 255) / 256, 256, 0, stream>>>(h16, W2, b2, out);
}

// Round 5
// 1025.213 us; speedup vs baseline: 4.6481x; 4.6481x over previous
//
#include <hip/hip_runtime.h>
#include <hip/hip_fp16.h>

#define NN 100000
#define NE 1600000
#define KORD 10
#define HID 64

// binned CSR build: 391 buckets of 256 destination nodes each
#define NBUK ((NN + 255) / 256)        // 391
#define BCAP 8192                      // per-bucket staging capacity (mean 4096, sd 64)
#define EPB  (NE / 256)                // 6250 edges per pass-A block (256 blocks exactly)
// padded CSR capacity: every node segment rounded up to 8 entries
#define CSR_CAP (NE + 8 * NN)          // 2.4M entries

typedef _Float16 half8v __attribute__((ext_vector_type(8)));
typedef _Float16 half4v __attribute__((ext_vector_type(4)));
typedef float float4v __attribute__((ext_vector_type(4)));
typedef unsigned uint4v __attribute__((ext_vector_type(4)));
typedef int int4v __attribute__((ext_vector_type(4)));

__device__ __forceinline__ float2 up2(unsigned u) {
    __half2 hh = *(__half2*)&u;
    return __half22float2(hh);
}
__device__ __forceinline__ unsigned pk2(float a, float b) {
    __half2 hh = __floats2half2_rn(a, b);
    return *(unsigned*)&hh;
}

// ---------------- binned CSR build ----------------
__global__ __launch_bounds__(512) void k_zero(int* __restrict__ gcnt,
                                              int* __restrict__ dhist,
                                              int* __restrict__ palloc) {
    int t = threadIdx.x;
    if (t < NBUK) gcnt[t] = 0;
    if (t < 64) dhist[t] = 0;
    if (t == 511) *palloc = 0;
}

// pass A: partition edges into per-destination-range buckets.
// record = (c & 255) << 24 | r   (r < 2^24 since NN = 100000)
__global__ __launch_bounds__(1024) void k_binA(const int* __restrict__ ei,
                                               int* __restrict__ gcnt,
                                               unsigned* __restrict__ staged) {
    __shared__ int lh[NBUK];
    __shared__ int lcur[NBUK];
    int t = threadIdx.x;
    int ebeg = blockIdx.x * EPB;
    int eend = min(ebeg + EPB, NE);
    for (int i = t; i < NBUK; i += 1024) lh[i] = 0;
    __syncthreads();
    for (int e = ebeg + t; e < eend; e += 1024)
        atomicAdd(&lh[ei[NE + e] >> 8], 1);
    __syncthreads();
    for (int i = t; i < NBUK; i += 1024)
        lcur[i] = lh[i] ? atomicAdd(&gcnt[i], lh[i]) : 0;
    __syncthreads();
    for (int e = ebeg + t; e < eend; e += 1024) {
        int r = ei[e], c = ei[NE + e];
        int bkt = c >> 8;
        int slot = atomicAdd(&lcur[bkt], 1);
        if (slot < BCAP)
            staged[(size_t)bkt * BCAP + slot] = ((unsigned)(c & 255) << 24) | (unsigned)r;
    }
}

// pass B: one block per bucket. LDS histogram + padded scan over the 256-node
// range, bucket base via global atomic allocator, then scatter into the
// bucket's contiguous csr window (L2-local writes). Node segments are
// 8-aligned and tail-padded with sentinel NN (zero row) so the gather loop
// is fully branchless. Emits cnt / dinv / seg{start,iters} for the range.
__global__ __launch_bounds__(512) void k_binB(const unsigned* __restrict__ staged,
                                              const int* __restrict__ gcnt,
                                              int* __restrict__ palloc,
                                              int* __restrict__ cnt,
                                              float* __restrict__ dinv,
                                              int* __restrict__ csr,
                                              int2* __restrict__ seg) {
    __shared__ unsigned lrec[BCAP];
    __shared__ int lcnt[256], lcur[256], ltmp[256];
    __shared__ int lbase;
    int b = blockIdx.x, t = threadIdx.x;
    int count = min(gcnt[b], BCAP);
    if (t < 256) lcnt[t] = 0;
    __syncthreads();
    for (int i = t; i < count; i += 512) {
        unsigned rec = staged[(size_t)b * BCAP + i];
        lrec[i] = rec;
        atomicAdd(&lcnt[rec >> 24], 1);
    }
    __syncthreads();
    int v = 0, plen = 0;
    if (t < 256) { v = lcnt[t]; plen = (v + 7) & ~7; ltmp[t] = plen; }
    __syncthreads();
    int x = plen;
    for (int off = 1; off < 256; off <<= 1) {
        int y = (t < 256 && t >= off) ? ltmp[t - off] : 0;
        __syncthreads();
        if (t < 256) { x += y; ltmp[t] = x; }
        __syncthreads();
    }
    if (t == 255) lbase = atomicAdd(palloc, x);   // x = padded bucket total
    __syncthreads();
    int start = 0;
    if (t < 256) {
        start = lbase + x - plen;
        lcur[t] = start;
        int node = b * 256 + t;
        if (node < NN) {
            cnt[node] = v;
            dinv[node] = rsqrtf((float)(v + 1));   // +1 self-loop
            seg[node] = make_int2(start, plen >> 3);
            for (int i = v; i < plen; ++i) csr[start + i] = NN;   // sentinel pad
        }
    }
    __syncthreads();
    for (int i = t; i < count; i += 512) {
        unsigned rec = lrec[i];
        int pos = atomicAdd(&lcur[rec >> 24], 1);
        csr[pos] = (int)(rec & 0xFFFFFFu);
    }
}

// ---------------- degree-sorted node permutation ----------------
__global__ __launch_bounds__(256) void k_dhist(const int* __restrict__ cnt,
                                               int* __restrict__ dhist) {
    __shared__ int lh[64];
    int t = threadIdx.x;
    if (t < 64) lh[t] = 0;
    __syncthreads();
    int i = blockIdx.x * 256 + t;
    if (i < NN) atomicAdd(&lh[min(cnt[i], 63)], 1);
    __syncthreads();
    if (t < 64 && lh[t]) atomicAdd(&dhist[t], lh[t]);
}

__global__ void k_dscan(int* __restrict__ dhist) {   // 64 threads, exclusive scan
    __shared__ int tmp[64];
    int t = threadIdx.x;
    int v = dhist[t];
    tmp[t] = v;
    __syncthreads();
    int x = v;
    for (int off = 1; off < 64; off <<= 1) {
        int y = (t >= off) ? tmp[t - off] : 0;
        __syncthreads();
        x += y;
        tmp[t] = x;
        __syncthreads();
    }
    dhist[t] = x - v;
}

__global__ __launch_bounds__(256) void k_dperm(const int* __restrict__ cnt,
                                               int* __restrict__ dhist,
                                               int* __restrict__ perm) {
    __shared__ int lh[64], lb[64];
    int t = threadIdx.x;
    if (t < 64) lh[t] = 0;
    __syncthreads();
    int i = blockIdx.x * 256 + t;
    int b = 0, my = 0;
    if (i < NN) { b = min(cnt[i], 63); my = atomicAdd(&lh[b], 1); }
    __syncthreads();
    if (t < 64) lb[t] = lh[t] ? atomicAdd(&dhist[t], lh[t]) : 0;
    __syncthreads();
    if (i < NN) perm[lb[b] + my] = i;
}

// zero sentinel row NN of the 4 rotation buffers
__global__ __launch_bounds__(256) void k_zrow(__half* __restrict__ a, __half* __restrict__ b,
                                              __half* __restrict__ c, __half* __restrict__ d) {
    int t = threadIdx.x;
    __half z = __float2half(0.f);
    size_t base = (size_t)NN * HID;
    if (t < 64)       a[base + t] = z;
    else if (t < 128) b[base + (t - 64)] = z;
    else if (t < 192) c[base + (t - 128)] = z;
    else              d[base + (t - 192)] = z;
}

// ---------- W1 transpose + fp16 cast ----------
__global__ __launch_bounds__(256) void k_prepw1(const float* __restrict__ W1,
                                                _Float16* __restrict__ W1T) {
    int f = blockIdx.x * 256 + threadIdx.x;
    int n = f >> 8, k = f & 255;
    W1T[f] = (_Float16)W1[k * 64 + n];
}

// ---------- GEMM1 via MFMA: h~ = dinv * relu(x @ W1 + b1) ----------
#define G1K 128
#define G1S 136
__global__ __launch_bounds__(256) void k_gemm1(const float* __restrict__ x,
                                               const _Float16* __restrict__ W1T,
                                               const float* __restrict__ b1,
                                               const float* __restrict__ dinv,
                                               __half* __restrict__ h) {
    __shared__ _Float16 A_lds[64 * G1S];
    __shared__ _Float16 B_lds[64 * G1S];
    int t = threadIdx.x;
    int wave = t >> 6, lane = t & 63;
    int quad = lane >> 4, m16 = lane & 15;
    int row0 = blockIdx.x * 64;

    float4v acc[4];
#pragma unroll
    for (int n4 = 0; n4 < 4; ++n4) acc[n4] = (float4v){0.f, 0.f, 0.f, 0.f};

    for (int c = 0; c < 2; ++c) {
        int k0 = c * G1K;
#pragma unroll
        for (int i = 0; i < 8; ++i) {
            int f = i * 256 + t;
            int r = f >> 5, c4 = f & 31;
            int grow = row0 + r;
            float4 v = (grow < NN) ? *(const float4*)&x[(size_t)grow * 256 + k0 + c4 * 4]
                                   : make_float4(0.f, 0.f, 0.f, 0.f);
            half4v hv = {(_Float16)v.x, (_Float16)v.y, (_Float16)v.z, (_Float16)v.w};
            *(half4v*)&A_lds[r * G1S + c4 * 4] = hv;
        }
#pragma unroll
        for (int i = 0; i < 4; ++i) {
            int f = i * 256 + t;
            int n = f >> 4, k8 = f & 15;
            *(half8v*)&B_lds[n * G1S + k8 * 8] =
                *(const half8v*)&W1T[n * 256 + k0 + k8 * 8];
        }
        __syncthreads();

#pragma unroll
        for (int s = 0; s < 4; ++s) {
            half8v af = *(const half8v*)&A_lds[(wave * 16 + m16) * G1S + s * 32 + quad * 8];
#pragma unroll
            for (int n4 = 0; n4 < 4; ++n4) {
                half8v bf = *(const half8v*)&B_lds[(n4 * 16 + m16) * G1S + s * 32 + quad * 8];
                acc[n4] = __builtin_amdgcn_mfma_f32_16x16x32_f16(af, bf, acc[n4], 0, 0, 0);
            }
        }
        __syncthreads();
    }

    float bv[4];
#pragma unroll
    for (int n4 = 0; n4 < 4; ++n4) bv[n4] = b1[n4 * 16 + m16];
#pragma unroll
    for (int r = 0; r < 4; ++r) {
        int grow = row0 + wave * 16 + quad * 4 + r;
        if (grow >= NN) continue;
        float dv = dinv[grow];
#pragma unroll
        for (int n4 = 0; n4 < 4; ++n4) {
            float v = dv * fmaxf(acc[n4][r] + bv[n4], 0.f);
            h[(size_t)grow * 64 + n4 * 16 + m16] = __float2half(v);
        }
    }
}

// ---------- fused propagation + Jacobi combine ----------
// 8 nodes/wave via degree-sorted perm; branchless 8-wide gather over the
// 8-aligned sentinel-padded CSR. The 12.8 MB feature table (gathered src
// rows, 16x reuse) is the ONLY data kept cacheable; all single-touch
// streams (csr, t0, acc, dst/hout) are nontemporal so they cannot evict it.
#define ACC8(u) { float2 f0 = up2((u).x), f1 = up2((u).y), f2 = up2((u).z), f3 = up2((u).w); \
    p[0] += f0.x; p[1] += f0.y; p[2] += f1.x; p[3] += f1.y; \
    p[4] += f2.x; p[5] += f2.y; p[6] += f3.x; p[7] += f3.y; }

__global__ __launch_bounds__(256) void k_prop(const int2* __restrict__ seg,
                                              const int* __restrict__ csr,
                                              const int* __restrict__ perm,
                                              const __half* __restrict__ src,
                                              const __half* __restrict__ t0,
                                              const float* __restrict__ dinv,
                                              __half* __restrict__ dst,
                                              __half* __restrict__ acc,
                                              __half* __restrict__ hout,
                                              float An, float Bn, float Cn,
                                              const float* __restrict__ coeffs,
                                              int cbase, int kidx, int init,
                                              int finalize, int unscale) {
    int slot = ((blockIdx.x * 256 + threadIdx.x) >> 6) * 8 + ((threadIdx.x & 63) >> 3);
    int ch8 = (threadIdx.x & 7) * 8;
    bool valid = slot < NN;
    int node = valid ? perm[slot] : 0;
    int2 sg = valid ? seg[node] : make_int2(0, 0);
    const int4v* cp = (const int4v*)(csr + sg.x);
    int iters = sg.y;

    float p[8];
#pragma unroll
    for (int i = 0; i < 8; ++i) p[i] = 0.f;

    for (int it = 0; it < iters; ++it) {
        int4v ia = __builtin_nontemporal_load(&cp[it * 2]);
        int4v ib = __builtin_nontemporal_load(&cp[it * 2 + 1]);
        uint4v u0 = *(const uint4v*)&src[(size_t)ia.x * HID + ch8];
        uint4v u1 = *(const uint4v*)&src[(size_t)ia.y * HID + ch8];
        uint4v u2 = *(const uint4v*)&src[(size_t)ia.z * HID + ch8];
        uint4v u3 = *(const uint4v*)&src[(size_t)ia.w * HID + ch8];
        uint4v u4 = *(const uint4v*)&src[(size_t)ib.x * HID + ch8];
        uint4v u5 = *(const uint4v*)&src[(size_t)ib.y * HID + ch8];
        uint4v u6 = *(const uint4v*)&src[(size_t)ib.z * HID + ch8];
        uint4v u7 = *(const uint4v*)&src[(size_t)ib.w * HID + ch8];
        ACC8(u0); ACC8(u1); ACC8(u2); ACC8(u3);
        ACC8(u4); ACC8(u5); ACC8(u6); ACC8(u7);
    }

    if (!valid) return;
    size_t idx = (size_t)node * HID + ch8;
    float dv = dinv[node];
    float dv2 = dv * dv;

    uint4v sr = *(const uint4v*)&src[idx];          // cacheable (part of table)
    float2 s01 = up2(sr.x), s23 = up2(sr.y), s45 = up2(sr.z), s67 = up2(sr.w);
    float sv[8] = {s01.x, s01.y, s23.x, s23.y, s45.x, s45.y, s67.x, s67.y};

    uint4v tr = __builtin_nontemporal_load((const uint4v*)&t0[idx]);
    float2 t01 = up2(tr.x), t23 = up2(tr.y), t45 = up2(tr.z), t67 = up2(tr.w);
    float tv[8] = {t01.x, t01.y, t23.x, t23.y, t45.x, t45.y, t67.x, t67.y};

    float v[8];
#pragma unroll
    for (int i = 0; i < 8; ++i)
        v[i] = An * dv2 * (p[i] + sv[i]) + Bn * sv[i] - Cn * tv[i];

    if (!finalize) {
        uint4v o;
        o.x = pk2(v[0], v[1]); o.y = pk2(v[2], v[3]);
        o.z = pk2(v[4], v[5]); o.w = pk2(v[6], v[7]);
        __builtin_nontemporal_store(o, (uint4v*)&dst[idx]);
    }

    float ck = coeffs[cbase + kidx];
    float av[8];
    if (init) {
        float c0 = coeffs[cbase];
#pragma unroll
        for (int i = 0; i < 8; ++i) av[i] = c0 * sv[i];
    } else {
        uint4v ar = __builtin_nontemporal_load((const uint4v*)&acc[idx]);
        float2 a01 = up2(ar.x), a23 = up2(ar.y), a45 = up2(ar.z), a67 = up2(ar.w);
        av[0] = a01.x; av[1] = a01.y; av[2] = a23.x; av[3] = a23.y;
        av[4] = a45.x; av[5] = a45.y; av[6] = a67.x; av[7] = a67.y;
    }
#pragma unroll
    for (int i = 0; i < 8; ++i) av[i] += ck * v[i];

    uint4v o;
    if (finalize) {
        float s = unscale ? (1.0f / dv) : 1.0f;
        o.x = pk2(s * fmaxf(av[0], 0.f), s * fmaxf(av[1], 0.f));
        o.y = pk2(s * fmaxf(av[2], 0.f), s * fmaxf(av[3], 0.f));
        o.z = pk2(s * fmaxf(av[4], 0.f), s * fmaxf(av[5], 0.f));
        o.w = pk2(s * fmaxf(av[6], 0.f), s * fmaxf(av[7], 0.f));
        __builtin_nontemporal_store(o, (uint4v*)&hout[idx]);
    } else {
        o.x = pk2(av[0], av[1]); o.y = pk2(av[2], av[3]);
        o.z = pk2(av[4], av[5]); o.w = pk2(av[6], av[7]);
        __builtin_nontemporal_store(o, (uint4v*)&acc[idx]);
    }
}

// ---------- GEMM2: out = h16 @ W2 + b2 ----------
__global__ __launch_bounds__(256) void k_gemm2(const __half* __restrict__ h,
                                               const float* __restrict__ W2,
                                               const float* __restrict__ b2,
                                               float* __restrict__ out) {
    __shared__ float W2s[64 * 32];
    __shared__ float b2s[32];
    int t = threadIdx.x;
    for (int i = t * 4; i < 64 * 32; i += 256 * 4)
        *(float4*)&W2s[i] = *(const float4*)&W2[i];
    if (t < 32) b2s[t] = b2[t];
    __syncthreads();

    int gid = blockIdx.x * 256 + t;
    int row = gid >> 3;
    int c4 = (t & 7) * 4;
    if (row >= NN) return;
    const __half* hr = h + (size_t)row * 64;
    float4 acc = *(const float4*)&b2s[c4];
#pragma unroll
    for (int k8 = 0; k8 < 8; ++k8) {
        uint4 raw = *(const uint4*)&hr[k8 * 8];
        float2 a01 = up2(raw.x), a23 = up2(raw.y), a45 = up2(raw.z), a67 = up2(raw.w);
        float a[8] = {a01.x, a01.y, a23.x, a23.y, a45.x, a45.y, a67.x, a67.y};
#pragma unroll
        for (int j = 0; j < 8; ++j) {
            float4 w = *(const float4*)&W2s[(k8 * 8 + j) * 32 + c4];
            acc.x += a[j] * w.x;
            acc.y += a[j] * w.y;
            acc.z += a[j] * w.z;
            acc.w += a[j] * w.w;
        }
    }
    *(float4*)&out[(size_t)row * 32 + c4] = acc;
}

extern "C" void kernel_launch(void* const* d_in, const int* in_sizes, int n_in,
                              void* d_out, int out_size, void* d_ws, size_t ws_size,
                              hipStream_t stream) {
    const float* x      = (const float*)d_in[0];
    const int*   ei     = (const int*)d_in[1];
    const float* W1     = (const float*)d_in[2];
    const float* b1     = (const float*)d_in[3];
    const float* coeffs = (const float*)d_in[4];
    const float* W2     = (const float*)d_in[5];
    const float* b2     = (const float*)d_in[6];
    float* out = (float*)d_out;

    char* ws = (char*)d_ws;
    size_t off = 0;
    auto alloc = [&](size_t bytes) { void* p = ws + off; off += (bytes + 255) & ~(size_t)255; return p; };
    int*      cnt    = (int*)alloc(NN * 4);
    float*    dinv   = (float*)alloc(NN * 4);
    int*      csr    = (int*)alloc((size_t)CSR_CAP * 4);
    int2*     seg    = (int2*)alloc((size_t)NN * 8);
    int*      dhist  = (int*)alloc(64 * 4);
    int*      perm   = (int*)alloc(NN * 4);
    int*      gcnt   = (int*)alloc(NBUK * 4);
    int*      palloc = (int*)alloc(4);
    unsigned* staged = (unsigned*)alloc((size_t)NBUK * BCAP * 4);
    _Float16* W1T    = (_Float16*)alloc(256 * 64 * 2);
    __half*   h16    = (__half*)alloc((size_t)(NN + 1) * HID * 2);   // +1 sentinel row
    __half*   bufA   = (__half*)alloc((size_t)(NN + 1) * HID * 2);
    __half*   bufB   = (__half*)alloc((size_t)(NN + 1) * HID * 2);
    __half*   bufC   = (__half*)alloc((size_t)(NN + 1) * HID * 2);
    __half*   accb   = (__half*)alloc((size_t)NN * HID * 2);

    const int BN = (NN + 255) / 256;
    const int BP = (NN + 31) / 32;          // 8 nodes/wave, 4 waves/block

    // --- binned CSR build (write-local scatter, 8-aligned padded segments) ---
    k_zero<<<1, 512, 0, stream>>>(gcnt, dhist, palloc);
    k_binA<<<256, 1024, 0, stream>>>(ei, gcnt, staged);
    k_binB<<<NBUK, 512, 0, stream>>>(staged, gcnt, palloc, cnt, dinv, csr, seg);

    // --- degree-sorted node permutation ---
    k_dhist<<<BN, 256, 0, stream>>>(cnt, dhist);
    k_dscan<<<1, 64, 0, stream>>>(dhist);
    k_dperm<<<BN, 256, 0, stream>>>(cnt, dhist, perm);
    k_zrow<<<1, 256, 0, stream>>>(h16, bufA, bufB, bufC);

    // --- h~ = dinv * relu(x @ W1 + b1) via MFMA ---
    k_prepw1<<<64, 256, 0, stream>>>(W1, W1T);
    k_gemm1<<<(NN + 63) / 64, 256, 0, stream>>>(x, W1T, b1, dinv, h16);

    __half* rot[4] = {h16, bufA, bufB, bufC};

    for (int l = 0; l < 2; ++l) {
        int cbase = l * (KORD + 1);
        k_prop<<<BP, 256, 0, stream>>>(seg, csr, perm, rot[0], rot[0], dinv,
                                       rot[1], accb, h16, 1.0f, 0.0f, 0.0f,
                                       coeffs, cbase, 1, 1, 0, 0);
        for (int k = 2; k <= KORD; ++k) {
            __half* dst = rot[k & 3];
            const __half* s1 = rot[(k - 1) & 3];
            const __half* s0 = rot[(k - 2) & 3];
            double n = k - 1, a = 0.5, b = 0.5;
            double An = (2*n + a + b + 1) * (2*n + a + b + 2) / (2 * (n + 1) * (n + a + b + 1));
            double Bn = (a*a - b*b) * (2*n + a + b + 1) / (2 * (n + 1) * (n + a + b + 1) * (2*n + a + b));
            double Cn = (n + a) * (n + b) * (2*n + a + b + 2) / ((n + 1) * (n + a + b + 1) * (2*n + a + b));
            k_prop<<<BP, 256, 0, stream>>>(seg, csr, perm, s1, s0, dinv,
                                           dst, accb, h16, (float)An, (float)Bn, (float)Cn,
                                           coeffs, cbase, k, 0,
                                           (k == KORD) ? 1 : 0, l);
        }
    }

    // out = h @ W2 + b2
    k_gemm2<<<(NN * 8 + 255) / 256, 256, 0, stream>>>(h16, W2, b2, out);
}

// Round 6
// 976.395 us; speedup vs baseline: 4.8805x; 1.0500x over previous
//
#include <hip/hip_runtime.h>
#include <hip/hip_fp16.h>

#define NN 100000
#define NE 1600000
#define KORD 10
#define HID 64

// binned CSR build: 391 buckets of 256 destination nodes each
#define NBUK ((NN + 255) / 256)        // 391
#define BCAP 8192                      // per-bucket staging capacity (mean 4096, sd 64)
#define EPB  (NE / 256)                // 6250 edges per pass-A block (256 blocks exactly)
// padded CSR capacity: every node segment rounded up to 8 entries
#define CSR_CAP (NE + 8 * NN)          // 2.4M entries

typedef _Float16 half8v __attribute__((ext_vector_type(8)));
typedef _Float16 half4v __attribute__((ext_vector_type(4)));
typedef float float4v __attribute__((ext_vector_type(4)));
typedef unsigned uint4v __attribute__((ext_vector_type(4)));
typedef int int4v __attribute__((ext_vector_type(4)));

__device__ __forceinline__ float2 up2(unsigned u) {
    __half2 hh = *(__half2*)&u;
    return __half22float2(hh);
}
__device__ __forceinline__ unsigned pk2(float a, float b) {
    __half2 hh = __floats2half2_rn(a, b);
    return *(unsigned*)&hh;
}

// ---------------- binned CSR build ----------------
__global__ __launch_bounds__(512) void k_zero(int* __restrict__ gcnt,
                                              int* __restrict__ dhist,
                                              int* __restrict__ palloc) {
    int t = threadIdx.x;
    if (t < NBUK) gcnt[t] = 0;
    if (t < 64) dhist[t] = 0;
    if (t == 511) *palloc = 0;
}

// pass A: partition edges into per-destination-range buckets.
// record = (c & 255) << 24 | r   (r < 2^24 since NN = 100000)
__global__ __launch_bounds__(1024) void k_binA(const int* __restrict__ ei,
                                               int* __restrict__ gcnt,
                                               unsigned* __restrict__ staged) {
    __shared__ int lh[NBUK];
    __shared__ int lcur[NBUK];
    int t = threadIdx.x;
    int ebeg = blockIdx.x * EPB;
    int eend = min(ebeg + EPB, NE);
    for (int i = t; i < NBUK; i += 1024) lh[i] = 0;
    __syncthreads();
    for (int e = ebeg + t; e < eend; e += 1024)
        atomicAdd(&lh[ei[NE + e] >> 8], 1);
    __syncthreads();
    for (int i = t; i < NBUK; i += 1024)
        lcur[i] = lh[i] ? atomicAdd(&gcnt[i], lh[i]) : 0;
    __syncthreads();
    for (int e = ebeg + t; e < eend; e += 1024) {
        int r = ei[e], c = ei[NE + e];
        int bkt = c >> 8;
        int slot = atomicAdd(&lcur[bkt], 1);
        if (slot < BCAP)
            staged[(size_t)bkt * BCAP + slot] = ((unsigned)(c & 255) << 24) | (unsigned)r;
    }
}

// pass B: one block per bucket. LDS histogram + padded scan over the 256-node
// range, bucket base via global atomic allocator, then scatter into the
// bucket's contiguous csr window (L2-local writes). Node segments are
// 8-aligned and tail-padded with sentinel NN (zero row) so the gather loop
// is fully branchless. Emits cnt / dinv / seg{start,iters} for the range.
__global__ __launch_bounds__(512) void k_binB(const unsigned* __restrict__ staged,
                                              const int* __restrict__ gcnt,
                                              int* __restrict__ palloc,
                                              int* __restrict__ cnt,
                                              float* __restrict__ dinv,
                                              int* __restrict__ csr,
                                              int2* __restrict__ seg) {
    __shared__ unsigned lrec[BCAP];
    __shared__ int lcnt[256], lcur[256], ltmp[256];
    __shared__ int lbase;
    int b = blockIdx.x, t = threadIdx.x;
    int count = min(gcnt[b], BCAP);
    if (t < 256) lcnt[t] = 0;
    __syncthreads();
    for (int i = t; i < count; i += 512) {
        unsigned rec = staged[(size_t)b * BCAP + i];
        lrec[i] = rec;
        atomicAdd(&lcnt[rec >> 24], 1);
    }
    __syncthreads();
    int v = 0, plen = 0;
    if (t < 256) { v = lcnt[t]; plen = (v + 7) & ~7; ltmp[t] = plen; }
    __syncthreads();
    int x = plen;
    for (int off = 1; off < 256; off <<= 1) {
        int y = (t < 256 && t >= off) ? ltmp[t - off] : 0;
        __syncthreads();
        if (t < 256) { x += y; ltmp[t] = x; }
        __syncthreads();
    }
    if (t == 255) lbase = atomicAdd(palloc, x);   // x = padded bucket total
    __syncthreads();
    int start = 0;
    if (t < 256) {
        start = lbase + x - plen;
        lcur[t] = start;
        int node = b * 256 + t;
        if (node < NN) {
            cnt[node] = v;
            dinv[node] = rsqrtf((float)(v + 1));   // +1 self-loop
            seg[node] = make_int2(start, plen >> 3);
            for (int i = v; i < plen; ++i) csr[start + i] = NN;   // sentinel pad
        }
    }
    __syncthreads();
    for (int i = t; i < count; i += 512) {
        unsigned rec = lrec[i];
        int pos = atomicAdd(&lcur[rec >> 24], 1);
        csr[pos] = (int)(rec & 0xFFFFFFu);
    }
}

// ---------------- degree-sorted node permutation ----------------
__global__ __launch_bounds__(256) void k_dhist(const int* __restrict__ cnt,
                                               int* __restrict__ dhist) {
    __shared__ int lh[64];
    int t = threadIdx.x;
    if (t < 64) lh[t] = 0;
    __syncthreads();
    int i = blockIdx.x * 256 + t;
    if (i < NN) atomicAdd(&lh[min(cnt[i], 63)], 1);
    __syncthreads();
    if (t < 64 && lh[t]) atomicAdd(&dhist[t], lh[t]);
}

__global__ void k_dscan(int* __restrict__ dhist) {   // 64 threads, exclusive scan
    __shared__ int tmp[64];
    int t = threadIdx.x;
    int v = dhist[t];
    tmp[t] = v;
    __syncthreads();
    int x = v;
    for (int off = 1; off < 64; off <<= 1) {
        int y = (t >= off) ? tmp[t - off] : 0;
        __syncthreads();
        x += y;
        tmp[t] = x;
        __syncthreads();
    }
    dhist[t] = x - v;
}

__global__ __launch_bounds__(256) void k_dperm(const int* __restrict__ cnt,
                                               int* __restrict__ dhist,
                                               int* __restrict__ perm) {
    __shared__ int lh[64], lb[64];
    int t = threadIdx.x;
    if (t < 64) lh[t] = 0;
    __syncthreads();
    int i = blockIdx.x * 256 + t;
    int b = 0, my = 0;
    if (i < NN) { b = min(cnt[i], 63); my = atomicAdd(&lh[b], 1); }
    __syncthreads();
    if (t < 64) lb[t] = lh[t] ? atomicAdd(&dhist[t], lh[t]) : 0;
    __syncthreads();
    if (i < NN) perm[lb[b] + my] = i;
}

// zero sentinel row NN of the 4 rotation buffers
__global__ __launch_bounds__(256) void k_zrow(__half* __restrict__ a, __half* __restrict__ b,
                                              __half* __restrict__ c, __half* __restrict__ d) {
    int t = threadIdx.x;
    __half z = __float2half(0.f);
    size_t base = (size_t)NN * HID;
    if (t < 64)       a[base + t] = z;
    else if (t < 128) b[base + (t - 64)] = z;
    else if (t < 192) c[base + (t - 128)] = z;
    else              d[base + (t - 192)] = z;
}

// ---------- W1 transpose + fp16 cast ----------
__global__ __launch_bounds__(256) void k_prepw1(const float* __restrict__ W1,
                                                _Float16* __restrict__ W1T) {
    int f = blockIdx.x * 256 + threadIdx.x;
    int n = f >> 8, k = f & 255;
    W1T[f] = (_Float16)W1[k * 64 + n];
}

// ---------- GEMM1 via MFMA: h~ = dinv * relu(x @ W1 + b1) ----------
#define G1K 128
#define G1S 136
__global__ __launch_bounds__(256) void k_gemm1(const float* __restrict__ x,
                                               const _Float16* __restrict__ W1T,
                                               const float* __restrict__ b1,
                                               const float* __restrict__ dinv,
                                               __half* __restrict__ h) {
    __shared__ _Float16 A_lds[64 * G1S];
    __shared__ _Float16 B_lds[64 * G1S];
    int t = threadIdx.x;
    int wave = t >> 6, lane = t & 63;
    int quad = lane >> 4, m16 = lane & 15;
    int row0 = blockIdx.x * 64;

    float4v acc[4];
#pragma unroll
    for (int n4 = 0; n4 < 4; ++n4) acc[n4] = (float4v){0.f, 0.f, 0.f, 0.f};

    for (int c = 0; c < 2; ++c) {
        int k0 = c * G1K;
#pragma unroll
        for (int i = 0; i < 8; ++i) {
            int f = i * 256 + t;
            int r = f >> 5, c4 = f & 31;
            int grow = row0 + r;
            float4 v = (grow < NN) ? *(const float4*)&x[(size_t)grow * 256 + k0 + c4 * 4]
                                   : make_float4(0.f, 0.f, 0.f, 0.f);
            half4v hv = {(_Float16)v.x, (_Float16)v.y, (_Float16)v.z, (_Float16)v.w};
            *(half4v*)&A_lds[r * G1S + c4 * 4] = hv;
        }
#pragma unroll
        for (int i = 0; i < 4; ++i) {
            int f = i * 256 + t;
            int n = f >> 4, k8 = f & 15;
            *(half8v*)&B_lds[n * G1S + k8 * 8] =
                *(const half8v*)&W1T[n * 256 + k0 + k8 * 8];
        }
        __syncthreads();

#pragma unroll
        for (int s = 0; s < 4; ++s) {
            half8v af = *(const half8v*)&A_lds[(wave * 16 + m16) * G1S + s * 32 + quad * 8];
#pragma unroll
            for (int n4 = 0; n4 < 4; ++n4) {
                half8v bf = *(const half8v*)&B_lds[(n4 * 16 + m16) * G1S + s * 32 + quad * 8];
                acc[n4] = __builtin_amdgcn_mfma_f32_16x16x32_f16(af, bf, acc[n4], 0, 0, 0);
            }
        }
        __syncthreads();
    }

    float bv[4];
#pragma unroll
    for (int n4 = 0; n4 < 4; ++n4) bv[n4] = b1[n4 * 16 + m16];
#pragma unroll
    for (int r = 0; r < 4; ++r) {
        int grow = row0 + wave * 16 + quad * 4 + r;
        if (grow >= NN) continue;
        float dv = dinv[grow];
#pragma unroll
        for (int n4 = 0; n4 < 4; ++n4) {
            float v = dv * fmaxf(acc[n4][r] + bv[n4], 0.f);
            h[(size_t)grow * 64 + n4 * 16 + m16] = __float2half(v);
        }
    }
}

// ---------- fused propagation + Jacobi combine ----------
// 8 nodes/wave via degree-sorted perm; branchless 8-wide gather over the
// 8-aligned sentinel-padded CSR. Scheduling polish vs the 995us baseline:
// (1) epilogue loads (src/t0/acc rows, dinv) hoisted ABOVE the gather loop
//     so their latency hides under the gather phase;
// (2) index loads software-pipelined (load it+1's indices before
//     accumulating it) to break the idx->gather serial chain;
// (3) float2 accumulation (v_pk_add_f32).
#define ACCV(u) { p01 += up2((u).x); p23 += up2((u).y); p45 += up2((u).z); p67 += up2((u).w); }

__global__ __launch_bounds__(256) void k_prop(const int2* __restrict__ seg,
                                              const int* __restrict__ csr,
                                              const int* __restrict__ perm,
                                              const __half* __restrict__ src,
                                              const __half* __restrict__ t0,
                                              const float* __restrict__ dinv,
                                              __half* __restrict__ dst,
                                              __half* __restrict__ acc,
                                              __half* __restrict__ hout,
                                              float An, float Bn, float Cn,
                                              const float* __restrict__ coeffs,
                                              int cbase, int kidx, int init,
                                              int finalize, int unscale) {
    int slot = ((blockIdx.x * 256 + threadIdx.x) >> 6) * 8 + ((threadIdx.x & 63) >> 3);
    int ch8 = (threadIdx.x & 7) * 8;
    bool valid = slot < NN;
    int node = valid ? perm[slot] : 0;
    int2 sg = valid ? seg[node] : make_int2(0, 0);
    const int4v* cp = (const int4v*)(csr + sg.x);
    int iters = sg.y;

    // hoisted loop-independent loads (row 0 is a safe dummy when !valid)
    size_t idx = (size_t)node * HID + ch8;
    float dv = dinv[node];
    float ck = coeffs[cbase + kidx];
    float c0 = coeffs[cbase];
    uint4v sr = *(const uint4v*)&src[idx];
    uint4v tr = *(const uint4v*)&t0[idx];
    uint4v ar = {0u, 0u, 0u, 0u};
    if (!init) ar = *(const uint4v*)&acc[idx];

    float2 p01 = {0.f, 0.f}, p23 = {0.f, 0.f}, p45 = {0.f, 0.f}, p67 = {0.f, 0.f};

    int4v ia, ib;
    if (iters > 0) { ia = cp[0]; ib = cp[1]; }
    for (int it = 0; it < iters; ++it) {
        uint4v u0 = *(const uint4v*)&src[(size_t)ia.x * HID + ch8];
        uint4v u1 = *(const uint4v*)&src[(size_t)ia.y * HID + ch8];
        uint4v u2 = *(const uint4v*)&src[(size_t)ia.z * HID + ch8];
        uint4v u3 = *(const uint4v*)&src[(size_t)ia.w * HID + ch8];
        uint4v u4 = *(const uint4v*)&src[(size_t)ib.x * HID + ch8];
        uint4v u5 = *(const uint4v*)&src[(size_t)ib.y * HID + ch8];
        uint4v u6 = *(const uint4v*)&src[(size_t)ib.z * HID + ch8];
        uint4v u7 = *(const uint4v*)&src[(size_t)ib.w * HID + ch8];
        if (it + 1 < iters) {            // prefetch next indices before the adds
            ia = cp[it * 2 + 2];
            ib = cp[it * 2 + 3];
        }
        ACCV(u0); ACCV(u1); ACCV(u2); ACCV(u3);
        ACCV(u4); ACCV(u5); ACCV(u6); ACCV(u7);
    }

    if (!valid) return;
    float dv2 = dv * dv;
    float p[8] = {p01.x, p01.y, p23.x, p23.y, p45.x, p45.y, p67.x, p67.y};

    float2 s01 = up2(sr.x), s23 = up2(sr.y), s45 = up2(sr.z), s67 = up2(sr.w);
    float sv[8] = {s01.x, s01.y, s23.x, s23.y, s45.x, s45.y, s67.x, s67.y};

    float2 t01 = up2(tr.x), t23 = up2(tr.y), t45 = up2(tr.z), t67 = up2(tr.w);
    float tv[8] = {t01.x, t01.y, t23.x, t23.y, t45.x, t45.y, t67.x, t67.y};

    float v[8];
#pragma unroll
    for (int i = 0; i < 8; ++i)
        v[i] = An * dv2 * (p[i] + sv[i]) + Bn * sv[i] - Cn * tv[i];

    if (!finalize) {
        uint4v o;
        o.x = pk2(v[0], v[1]); o.y = pk2(v[2], v[3]);
        o.z = pk2(v[4], v[5]); o.w = pk2(v[6], v[7]);
        *(uint4v*)&dst[idx] = o;
    }

    float av[8];
    if (init) {
#pragma unroll
        for (int i = 0; i < 8; ++i) av[i] = c0 * sv[i];
    } else {
        float2 a01 = up2(ar.x), a23 = up2(ar.y), a45 = up2(ar.z), a67 = up2(ar.w);
        av[0] = a01.x; av[1] = a01.y; av[2] = a23.x; av[3] = a23.y;
        av[4] = a45.x; av[5] = a45.y; av[6] = a67.x; av[7] = a67.y;
    }
#pragma unroll
    for (int i = 0; i < 8; ++i) av[i] += ck * v[i];

    uint4v o;
    if (finalize) {
        float s = unscale ? (1.0f / dv) : 1.0f;
        o.x = pk2(s * fmaxf(av[0], 0.f), s * fmaxf(av[1], 0.f));
        o.y = pk2(s * fmaxf(av[2], 0.f), s * fmaxf(av[3], 0.f));
        o.z = pk2(s * fmaxf(av[4], 0.f), s * fmaxf(av[5], 0.f));
        o.w = pk2(s * fmaxf(av[6], 0.f), s * fmaxf(av[7], 0.f));
        *(uint4v*)&hout[idx] = o;
    } else {
        o.x = pk2(av[0], av[1]); o.y = pk2(av[2], av[3]);
        o.z = pk2(av[4], av[5]); o.w = pk2(av[6], av[7]);
        *(uint4v*)&acc[idx] = o;
    }
}

// ---------- GEMM2: out = h16 @ W2 + b2 ----------
__global__ __launch_bounds__(256) void k_gemm2(const __half* __restrict__ h,
                                               const float* __restrict__ W2,
                                               const float* __restrict__ b2,
                                               float* __restrict__ out) {
    __shared__ float W2s[64 * 32];
    __shared__ float b2s[32];
    int t = threadIdx.x;
    for (int i = t * 4; i < 64 * 32; i += 256 * 4)
        *(float4*)&W2s[i] = *(const float4*)&W2[i];
    if (t < 32) b2s[t] = b2[t];
    __syncthreads();

    int gid = blockIdx.x * 256 + t;
    int row = gid >> 3;
    int c4 = (t & 7) * 4;
    if (row >= NN) return;
    const __half* hr = h + (size_t)row * 64;
    float4 acc = *(const float4*)&b2s[c4];
#pragma unroll
    for (int k8 = 0; k8 < 8; ++k8) {
        uint4 raw = *(const uint4*)&hr[k8 * 8];
        float2 a01 = up2(raw.x), a23 = up2(raw.y), a45 = up2(raw.z), a67 = up2(raw.w);
        float a[8] = {a01.x, a01.y, a23.x, a23.y, a45.x, a45.y, a67.x, a67.y};
#pragma unroll
        for (int j = 0; j < 8; ++j) {
            float4 w = *(const float4*)&W2s[(k8 * 8 + j) * 32 + c4];
            acc.x += a[j] * w.x;
            acc.y += a[j] * w.y;
            acc.z += a[j] * w.z;
            acc.w += a[j] * w.w;
        }
    }
    *(float4*)&out[(size_t)row * 32 + c4] = acc;
}

extern "C" void kernel_launch(void* const* d_in, const int* in_sizes, int n_in,
                              void* d_out, int out_size, void* d_ws, size_t ws_size,
                              hipStream_t stream) {
    const float* x      = (const float*)d_in[0];
    const int*   ei     = (const int*)d_in[1];
    const float* W1     = (const float*)d_in[2];
    const float* b1     = (const float*)d_in[3];
    const float* coeffs = (const float*)d_in[4];
    const float* W2     = (const float*)d_in[5];
    const float* b2     = (const float*)d_in[6];
    float* out = (float*)d_out;

    char* ws = (char*)d_ws;
    size_t off = 0;
    auto alloc = [&](size_t bytes) { void* p = ws + off; off += (bytes + 255) & ~(size_t)255; return p; };
    int*      cnt    = (int*)alloc(NN * 4);
    float*    dinv   = (float*)alloc(NN * 4);
    int*      csr    = (int*)alloc((size_t)CSR_CAP * 4);
    int2*     seg    = (int2*)alloc((size_t)NN * 8);
    int*      dhist  = (int*)alloc(64 * 4);
    int*      perm   = (int*)alloc(NN * 4);
    int*      gcnt   = (int*)alloc(NBUK * 4);
    int*      palloc = (int*)alloc(4);
    unsigned* staged = (unsigned*)alloc((size_t)NBUK * BCAP * 4);
    _Float16* W1T    = (_Float16*)alloc(256 * 64 * 2);
    __half*   h16    = (__half*)alloc((size_t)(NN + 1) * HID * 2);   // +1 sentinel row
    __half*   bufA   = (__half*)alloc((size_t)(NN + 1) * HID * 2);
    __half*   bufB   = (__half*)alloc((size_t)(NN + 1) * HID * 2);
    __half*   bufC   = (__half*)alloc((size_t)(NN + 1) * HID * 2);
    __half*   accb   = (__half*)alloc((size_t)NN * HID * 2);

    const int BN = (NN + 255) / 256;
    const int BP = (NN + 31) / 32;          // 8 nodes/wave, 4 waves/block

    // --- binned CSR build (write-local scatter, 8-aligned padded segments) ---
    k_zero<<<1, 512, 0, stream>>>(gcnt, dhist, palloc);
    k_binA<<<256, 1024, 0, stream>>>(ei, gcnt, staged);
    k_binB<<<NBUK, 512, 0, stream>>>(staged, gcnt, palloc, cnt, dinv, csr, seg);

    // --- degree-sorted node permutation ---
    k_dhist<<<BN, 256, 0, stream>>>(cnt, dhist);
    k_dscan<<<1, 64, 0, stream>>>(dhist);
    k_dperm<<<BN, 256, 0, stream>>>(cnt, dhist, perm);
    k_zrow<<<1, 256, 0, stream>>>(h16, bufA, bufB, bufC);

    // --- h~ = dinv * relu(x @ W1 + b1) via MFMA ---
    k_prepw1<<<64, 256, 0, stream>>>(W1, W1T);
    k_gemm1<<<(NN + 63) / 64, 256, 0, stream>>>(x, W1T, b1, dinv, h16);

    __half* rot[4] = {h16, bufA, bufB, bufC};

    for (int l = 0; l < 2; ++l) {
        int cbase = l * (KORD + 1);
        k_prop<<<BP, 256, 0, stream>>>(seg, csr, perm, rot[0], rot[0], dinv,
                                       rot[1], accb, h16, 1.0f, 0.0f, 0.0f,
                                       coeffs, cbase, 1, 1, 0, 0);
        for (int k = 2; k <= KORD; ++k) {
            __half* dst = rot[k & 3];
            const __half* s1 = rot[(k - 1) & 3];
            const __half* s0 = rot[(k - 2) & 3];
            double n = k - 1, a = 0.5, b = 0.5;
            double An = (2*n + a + b + 1) * (2*n + a + b + 2) / (2 * (n + 1) * (n + a + b + 1));
            double Bn = (a*a - b*b) * (2*n + a + b + 1) / (2 * (n + 1) * (n + a + b + 1) * (2*n + a + b));
            double Cn = (n + a) * (n + b) * (2*n + a + b + 2) / ((n + 1) * (n + a + b + 1) * (2*n + a + b));
            k_prop<<<BP, 256, 0, stream>>>(seg, csr, perm, s1, s0, dinv,
                                           dst, accb, h16, (float)An, (float)Bn, (float)Cn,
                                           coeffs, cbase, k, 0,
                                           (k == KORD) ? 1 : 0, l);
        }
    }

    // out = h @ W2 + b2
    k_gemm2<<<(NN * 8 + 255) / 256, 256, 0, stream>>>(h16, W2, b2, out);
}